// Round 8
// baseline (5780.445 us; speedup 1.0000x reference)
//
#include <hip/hip_runtime.h>

#define B 256
#define T 2048
#define HDIM 128
#define HSTR 136   // f16 row stride of H tile (272 B; pad breaks bank alignment)

typedef _Float16 f16;
typedef _Float16 h2 __attribute__((ext_vector_type(2)));
typedef _Float16 f16x8 __attribute__((ext_vector_type(8)));
typedef float f32x4 __attribute__((ext_vector_type(4)));

__device__ __forceinline__ float dot2(h2 a, h2 b, float c) {
#if __has_builtin(__builtin_amdgcn_fdot2)
    return __builtin_amdgcn_fdot2(a, b, c, false);
#else
    return c + (float)a[0] * (float)b[0] + (float)a[1] * (float)b[1];
#endif
}

__device__ __forceinline__ float rcp_(float x) {
#if __has_builtin(__builtin_amdgcn_rcpf)
    return __builtin_amdgcn_rcpf(x);
#else
    return 1.0f / x;
#endif
}
// approx activations via v_rcp (~1e-6 rel err; threshold is 1e-2)
__device__ __forceinline__ float sigm(float x) { return rcp_(1.0f + __expf(-x)); }
// tanh(x) = 2*sigm(2x)-1 ; correct saturation at +/-inf, no abs/copysign needed
__device__ __forceinline__ float tanh2(float x) {
    return fmaf(2.0f, rcp_(1.0f + __expf(-2.0f * x)), -1.0f);
}

__device__ __forceinline__ void bar() {
    // LDS-only barrier: order ds ops but do NOT drain vmcnt (x prefetch + y
    // stores stay in flight across the barrier).
    asm volatile("s_waitcnt lgkmcnt(0)" ::: "memory");
    __builtin_amdgcn_s_barrier();
}

// ---------------- fc1: scent[B,T,3] -> x1[T,B,32] f16 (24 real + 8 zero pad) ---------
__global__ __launch_bounds__(256) void fc1_kernel(
    const float* __restrict__ scent,
    const float* __restrict__ W1, const float* __restrict__ b1,
    const float* __restrict__ W2, const float* __restrict__ b2,
    f16* __restrict__ x1) {
    int r = blockIdx.x * 256 + threadIdx.x;   // r = b*T + t
    int b = r >> 11, t = r & 2047;
    float s0 = scent[r * 3], s1 = scent[r * 3 + 1], s2 = scent[r * 3 + 2];
    float a[12];
#pragma unroll
    for (int i = 0; i < 12; i++) {
        float v = W1[i * 3] * s0 + W1[i * 3 + 1] * s1 + W1[i * 3 + 2] * s2 + b1[i];
        a[i] = fmaxf(v, 0.f);
    }
    union { f16 o[32]; uint4 u[4]; } U;
#pragma unroll
    for (int j = 0; j < 24; j++) {
        float v = b2[j];
#pragma unroll
        for (int i = 0; i < 12; i++) v = fmaf(W2[j * 12 + i], a[i], v);
        U.o[j] = (f16)fmaxf(v, 0.f);
    }
#pragma unroll
    for (int j = 24; j < 32; j++) U.o[j] = (f16)0.f;
    uint4* d4 = (uint4*)(x1 + ((size_t)t * B + b) * 32);
#pragma unroll
    for (int i = 0; i < 4; i++) d4[i] = U.u[i];
}

// ---------------- pack Wf1 f32 -> half2 ----------------
__global__ __launch_bounds__(256) void pack_kernel(const float* __restrict__ w,
                                                   unsigned int* __restrict__ o) {
    int i = blockIdx.x * 256 + threadIdx.x;
    if (i < 4096) {
        union { h2 h; unsigned int u; } U;
        U.h[0] = (f16)w[2 * i];
        U.h[1] = (f16)w[2 * i + 1];
        o[i] = U.u;
    }
}

// ---------------- fused MFMA LSTM layer: 16 batch rows per block, whole T ----------
// 512 thr = 8 waves; wave w owns unit group [16w,16w+16): 4 gate-class tiles
// (i,f,g,o), each 16x16. Per step:
//   rec : gates = H[16,128] @ Whh^T  -- 16 MFMA/wave, C-in = gx(t)+bias regs
//   gx  : gx(t+1) = x(t+1) @ Wih^T   -- KF*4 MFMA/wave into second acc set
//   act + c/h update fully in-register (lane holds 4 (row,unit) cells)
//   h -> LDS tile (double-buffered, pad-136 stride), ONE barrier/step.
// Fragment layouts as verified in r5-r7 gx_gemm: A row=l&15 k=8*(l>>4)+j;
// B col=l&15 same k; C row=4*(l>>4)+q col=l&15.
template <int KF, int KREAL>
__global__ __attribute__((amdgpu_flat_work_group_size(512, 512), amdgpu_waves_per_eu(2, 2)))
void lstm_mfma(
    const f16* x,                    // [T][B][KIN], KIN = KF*32 (may alias y)
    const float* __restrict__ Wih,   // [512][KREAL]
    const float* __restrict__ Whh,   // [512][128]
    const float* __restrict__ bih, const float* __restrict__ bhh,
    f16* y,                          // [T][B][128]
    float* __restrict__ hT, float* __restrict__ cT) {   // [B][128]
    constexpr int KIN = KF * 32;
    __shared__ __align__(16) f16 H[2][16 * HSTR];
    const int tid = threadIdx.x;
    const int l = tid & 63, w = tid >> 6;
    const int lc = l & 15, lg = l >> 4;
    const int rb = blockIdx.x * 16;

    // ---- B-frags (one-time): Whh 16, Wih KF*4, biases ----
    f16x8 whB[4][4];
    f16x8 wiB[4][KF];
    float bias[4];
#pragma unroll
    for (int tt = 0; tt < 4; tt++) {
        int g = 128 * tt + 16 * w + lc;
        bias[tt] = bih[g] + bhh[g];
        const float* wr = Whh + (size_t)g * HDIM;
#pragma unroll
        for (int kf = 0; kf < 4; kf++) {
            f16x8 v;
#pragma unroll
            for (int j = 0; j < 8; j++) v[j] = (f16)wr[kf * 32 + lg * 8 + j];
            whB[tt][kf] = v;
        }
        const float* wi = Wih + (size_t)g * KREAL;
#pragma unroll
        for (int kf = 0; kf < KF; kf++) {
            f16x8 v;
#pragma unroll
            for (int j = 0; j < 8; j++) {
                int k = kf * 32 + lg * 8 + j;
                v[j] = (k < KREAL) ? (f16)wi[k] : (f16)0.f;
            }
            wiB[tt][kf] = v;
        }
    }

    // ---- zero H[0] (h_{-1} = 0) ----
    for (int i = tid; i < 16 * HSTR / 2; i += 512) ((unsigned int*)&H[0][0])[i] = 0u;

    f32x4 cst = {0.f, 0.f, 0.f, 0.f};
    float hl[4] = {0.f, 0.f, 0.f, 0.f};

    // per-lane x A-frag base: row rb+lc, k offset lg*8
    const f16* xbase = x + (size_t)(rb + lc) * KIN + lg * 8;

    // ---- prologue: gA = gx(0)+bias ; xe = x(1) ----
    f32x4 gA[4], gB[4];
    f16x8 xe[KF], xo[KF];
#pragma unroll
    for (int kf = 0; kf < KF; kf++) xe[kf] = *(const f16x8*)(xbase + kf * 32);   // x(0)
#pragma unroll
    for (int tt = 0; tt < 4; tt++) gA[tt] = (f32x4){bias[tt], bias[tt], bias[tt], bias[tt]};
#pragma unroll
    for (int kf = 0; kf < KF; kf++)
#pragma unroll
        for (int tt = 0; tt < 4; tt++)
            gA[tt] = __builtin_amdgcn_mfma_f32_16x16x32_f16(xe[kf], wiB[tt][kf], gA[tt], 0, 0, 0);
#pragma unroll
    for (int kf = 0; kf < KF; kf++)
        xe[kf] = *(const f16x8*)(xbase + (size_t)1 * B * KIN + kf * 32);          // x(1)
    __syncthreads();

#define STEP(t, HR, HW, GXC, GXN, XC, XN)                                                     \
    {                                                                                          \
        f16x8 hA[4];                                                                           \
        const char* hr = (const char*)&H[HR][0];                                               \
        _Pragma("unroll")                                                                      \
        for (int kf = 0; kf < 4; kf++)                                                         \
            hA[kf] = *(const f16x8*)(hr + lc * (HSTR * 2) + 64 * kf + 16 * lg);                \
        _Pragma("unroll")                                                                      \
        for (int kf = 0; kf < 4; kf++) {                                                       \
            _Pragma("unroll")                                                                  \
            for (int tt = 0; tt < 4; tt++)                                                     \
                GXC[tt] = __builtin_amdgcn_mfma_f32_16x16x32_f16(hA[kf], whB[tt][kf],          \
                                                                 GXC[tt], 0, 0, 0);            \
        }                                                                                      \
        _Pragma("unroll")                                                                      \
        for (int tt = 0; tt < 4; tt++)                                                         \
            GXN[tt] = (f32x4){bias[tt], bias[tt], bias[tt], bias[tt]};                         \
        _Pragma("unroll")                                                                      \
        for (int kf = 0; kf < KF; kf++) {                                                      \
            _Pragma("unroll")                                                                  \
            for (int tt = 0; tt < 4; tt++)                                                     \
                GXN[tt] = __builtin_amdgcn_mfma_f32_16x16x32_f16(XC[kf], wiB[tt][kf],          \
                                                                 GXN[tt], 0, 0, 0);            \
        }                                                                                      \
        {                                                                                      \
            int tl = (t) + 2; if (tl > T - 1) tl = T - 1;                                      \
            _Pragma("unroll")                                                                  \
            for (int kf = 0; kf < KF; kf++)                                                    \
                XN[kf] = *(const f16x8*)(xbase + (size_t)tl * B * KIN + kf * 32);              \
        }                                                                                      \
        char* hw = (char*)&H[HW][0];                                                           \
        _Pragma("unroll")                                                                      \
        for (int q = 0; q < 4; q++) {                                                          \
            float gi_ = sigm(GXC[0][q]), gf_ = sigm(GXC[1][q]);                                \
            float gg_ = tanh2(GXC[2][q]), go_ = sigm(GXC[3][q]);                               \
            cst[q] = gf_ * cst[q] + gi_ * gg_;                                                 \
            float hh = go_ * tanh2(cst[q]);                                                    \
            hl[q] = hh;                                                                        \
            f16 h16 = (f16)hh;                                                                 \
            *(f16*)(hw + (4 * lg + q) * (HSTR * 2) + (16 * w + lc) * 2) = h16;                 \
            y[((size_t)(t) * B + rb + 4 * lg + q) * HDIM + 16 * w + lc] = h16;                 \
        }                                                                                      \
        bar();                                                                                 \
    }

    for (int t = 0; t < T; t += 2) {
        STEP(t, 0, 1, gA, gB, xe, xo)
        STEP(t + 1, 1, 0, gB, gA, xo, xe)
    }
#undef STEP

    // ---- final h/c -> outputs ----
#pragma unroll
    for (int q = 0; q < 4; q++) {
        hT[(size_t)(rb + 4 * lg + q) * HDIM + 16 * w + lc] = hl[q];
        cT[(size_t)(rb + 4 * lg + q) * HDIM + 16 * w + lc] = cst[q];
    }
}

// ---------------- fc2: y[T,B,128] f16 -> out[B,T,32] f32 ----------------
__global__ __launch_bounds__(256) void fc2_kernel(
    const f16* __restrict__ yin,
    const unsigned int* __restrict__ w1,  // [64][64] half2-packed Wf1
    const float* __restrict__ bf1,
    const float* __restrict__ Wf2,        // [32][64] f32
    const float* __restrict__ bf2,
    float* __restrict__ out) {
    int r = blockIdx.x * 256 + threadIdx.x;   // r = t*B + b
    union { uint4 u4[16]; h2 h[64]; } Y;
    {
        const uint4* yr4 = (const uint4*)(yin + (size_t)r * 128);
#pragma unroll
        for (int i = 0; i < 16; i++) Y.u4[i] = yr4[i];
    }
    float acc2[32];
#pragma unroll
    for (int i = 0; i < 32; i++) acc2[i] = 0.f;

    for (int cO = 0; cO < 64; cO++) {   // rolled: z1[cO] consumed immediately
        float a0 = bf1[cO], a1 = 0.f, a2 = 0.f, a3 = 0.f;
#pragma unroll
        for (int kk = 0; kk < 64; kk += 4) {
            union { unsigned int u; h2 h; } W0, W1x, W2x, W3;
            W0.u = w1[cO * 64 + kk];      a0 = dot2(W0.h,  Y.h[kk],     a0);
            W1x.u = w1[cO * 64 + kk + 1]; a1 = dot2(W1x.h, Y.h[kk + 1], a1);
            W2x.u = w1[cO * 64 + kk + 2]; a2 = dot2(W2x.h, Y.h[kk + 2], a2);
            W3.u = w1[cO * 64 + kk + 3];  a3 = dot2(W3.h,  Y.h[kk + 3], a3);
        }
        float a = fmaxf((a0 + a1) + (a2 + a3), 0.f);
#pragma unroll
        for (int c2 = 0; c2 < 32; c2++) acc2[c2] = fmaf(a, Wf2[c2 * 64 + cO], acc2[c2]);
    }
    float* orow = out + ((size_t)(r & 255) * T + (r >> 8)) * 32;
#pragma unroll
    for (int c2 = 0; c2 < 32; c2++) orow[c2] = fmaxf(acc2[c2] + bf2[c2], 0.f);
}

// ---------------- launch ----------------
extern "C" void kernel_launch(void* const* d_in, const int* in_sizes, int n_in,
                              void* d_out, int out_size, void* d_ws, size_t ws_size,
                              hipStream_t stream) {
    const float* scent = (const float*)d_in[0];
    const float* W1 = (const float*)d_in[1];
    const float* b1 = (const float*)d_in[2];
    const float* W2 = (const float*)d_in[3];
    const float* b2 = (const float*)d_in[4];
    const float* Wih[3] = {(const float*)d_in[5], (const float*)d_in[9], (const float*)d_in[13]};
    const float* Whh[3] = {(const float*)d_in[6], (const float*)d_in[10], (const float*)d_in[14]};
    const float* bihp[3] = {(const float*)d_in[7], (const float*)d_in[11], (const float*)d_in[15]};
    const float* bhhp[3] = {(const float*)d_in[8], (const float*)d_in[12], (const float*)d_in[16]};
    const float* Wf1 = (const float*)d_in[17];
    const float* bf1 = (const float*)d_in[18];
    const float* Wf2 = (const float*)d_in[19];
    const float* bf2 = (const float*)d_in[20];

    const size_t o_x1 = 0;                       // 32 MB: x1 [T,B,32] f16
    const size_t o_y  = 33554432;                // 128 MB: yb [T,B,128] f16
    const size_t o_w1 = o_y + 134217728;         // 16 KB: packed Wf1
    const size_t need = o_w1 + 16384;
    if (ws_size < need) return;

    char* ws = (char*)d_ws;
    f16* x1 = (f16*)(ws + o_x1);
    f16* yb = (f16*)(ws + o_y);
    unsigned int* w1p = (unsigned int*)(ws + o_w1);

    float* out = (float*)d_out;
    float* hO = out + (size_t)B * T * 32;
    float* cO = hO + 3 * B * HDIM;

    pack_kernel<<<16, 256, 0, stream>>>(Wf1, w1p);
    fc1_kernel<<<(B * T) / 256, 256, 0, stream>>>(scent, W1, b1, W2, b2, x1);

    lstm_mfma<1, 24><<<16, 512, 0, stream>>>(x1, Wih[0], Whh[0], bihp[0], bhhp[0],
                                             yb, hO, cO);
    lstm_mfma<4, 128><<<16, 512, 0, stream>>>(yb, Wih[1], Whh[1], bihp[1], bhhp[1],
                                              yb, hO + B * HDIM, cO + B * HDIM);
    lstm_mfma<4, 128><<<16, 512, 0, stream>>>(yb, Wih[2], Whh[2], bihp[2], bhhp[2],
                                              yb, hO + 2 * B * HDIM, cO + 2 * B * HDIM);

    fc2_kernel<<<(B * T) / 256, 256, 0, stream>>>(yb, w1p, bf1, Wf2, bf2, out);
}